// Round 1
// baseline (96.261 us; speedup 1.0000x reference)
//
#include <hip/hip_runtime.h>
#include <math.h>

#define DIM 16
#define N_OPS 30

__device__ inline float2 cmul(float2 a, float2 b) {
    return make_float2(a.x * b.x - a.y * b.y, a.x * b.y + a.y * b.x);
}
__device__ inline float2 cadd(float2 a, float2 b) {
    return make_float2(a.x + b.x, a.y + b.y);
}

// Kernel A: one block of 256 threads. Builds the fixed 16x16 unitary in LDS
// (thread tid owns element (r=tid>>4, c=tid&15)), then computes the b=0 state
// pipeline and writes the scalar qk = |final_state[0]| to qk_out[0].
__global__ __launch_bounds__(256) void build_qk_kernel(
    const float* __restrict__ x, const float* __restrict__ y,
    const float* __restrict__ rand_angles, const float* __restrict__ rx_param,
    const float* __restrict__ ry_param, float* __restrict__ qk_out) {
    __shared__ float2 bufA[256];
    __shared__ float2 bufB[256];
    __shared__ float2 stv[DIM];
    __shared__ float2 stv2[DIM];

    const int tid = threadIdx.x;
    const int r = tid >> 4;
    const int c = tid & 15;

    float2* cur = bufA;
    float2* nxt = bufB;

    // U = I
    cur[tid] = make_float2((r == c) ? 1.0f : 0.0f, 0.0f);
    __syncthreads();

    // 30 random-layer gates: t == w == i%4.
    // t=0: RX(wire0), t=1: RY(wire1), t=2: RZ(wire2), t=3: CNOT(c=3, t=0).
    for (int i = 0; i < N_OPS; ++i) {
        const int t = i & 3;
        const int w = i & 3;
        float2 nv;
        if (t < 3) {
            const float h = 0.5f * rand_angles[i];
            const float ch = cosf(h);
            const float sh = sinf(h);
            float2 g00, g01, g10, g11;
            if (t == 0) {            // RX: [[c, -i s], [-i s, c]]
                g00 = make_float2(ch, 0.0f);  g01 = make_float2(0.0f, -sh);
                g10 = make_float2(0.0f, -sh); g11 = make_float2(ch, 0.0f);
            } else if (t == 1) {     // RY: [[c, -s], [s, c]]
                g00 = make_float2(ch, 0.0f);  g01 = make_float2(-sh, 0.0f);
                g10 = make_float2(sh, 0.0f);  g11 = make_float2(ch, 0.0f);
            } else {                 // RZ: diag(e^{-ih}, e^{ih})
                g00 = make_float2(ch, -sh);   g01 = make_float2(0.0f, 0.0f);
                g10 = make_float2(0.0f, 0.0f); g11 = make_float2(ch, sh);
            }
            const int p = 3 - w;                 // wire w lives on bit 3-w
            const int rp = (r >> p) & 1;
            const int r0 = r & ~(1 << p);
            const int r1 = r0 | (1 << p);
            const float2 ga = rp ? g10 : g00;
            const float2 gb = rp ? g11 : g01;
            nv = cadd(cmul(ga, cur[(r0 << 4) | c]), cmul(gb, cur[(r1 << 4) | c]));
        } else {
            // CNOT(control=w, target=(w+1)%4): row permutation (involution)
            const int cw = w;
            const int tw = (w + 1) & 3;
            const int pc = 3 - cw;
            const int pt = 3 - tw;
            const int src = ((r >> pc) & 1) ? (r ^ (1 << pt)) : r;
            nv = cur[(src << 4) | c];
        }
        nxt[tid] = nv;
        __syncthreads();
        float2* tmp = cur; cur = nxt; nxt = tmp;
    }

    // Trainable layer: for w in 0..3: U = RX_w @ U; U = RY_w @ U.
    const float rxa = rx_param[0];
    const float rya = ry_param[0];
    for (int w = 0; w < 4; ++w) {
        for (int k = 0; k < 2; ++k) {
            const float h = 0.5f * (k == 0 ? rxa : rya);
            const float ch = cosf(h);
            const float sh = sinf(h);
            float2 g00, g01, g10, g11;
            if (k == 0) {            // RX
                g00 = make_float2(ch, 0.0f);  g01 = make_float2(0.0f, -sh);
                g10 = make_float2(0.0f, -sh); g11 = make_float2(ch, 0.0f);
            } else {                 // RY
                g00 = make_float2(ch, 0.0f);  g01 = make_float2(-sh, 0.0f);
                g10 = make_float2(sh, 0.0f);  g11 = make_float2(ch, 0.0f);
            }
            const int p = 3 - w;
            const int rp = (r >> p) & 1;
            const int r0 = r & ~(1 << p);
            const int r1 = r0 | (1 << p);
            const float2 ga = rp ? g10 : g00;
            const float2 gb = rp ? g11 : g01;
            const float2 nv = cadd(cmul(ga, cur[(r0 << 4) | c]), cmul(gb, cur[(r1 << 4) | c]));
            nxt[tid] = nv;
            __syncthreads();
            float2* tmp = cur; cur = nxt; nxt = tmp;
        }
    }

    // b=0 state pipeline. encode_ry(e0, x[0]) — RY gates are real, serial on t0.
    if (tid == 0) {
        float2 s[DIM];
        for (int i = 0; i < DIM; ++i) s[i] = make_float2(0.0f, 0.0f);
        s[0] = make_float2(1.0f, 0.0f);
        for (int w = 0; w < 4; ++w) {
            const float h = 0.5f * x[w];         // x[0, w]
            const float ch = cosf(h);
            const float sh = sinf(h);
            const int p = 3 - w;
            for (int r0 = 0; r0 < DIM; ++r0) {
                if ((r0 >> p) & 1) continue;
                const int r1 = r0 | (1 << p);
                const float2 s0 = s[r0];
                const float2 s1 = s[r1];
                s[r0] = make_float2(ch * s0.x - sh * s1.x, ch * s0.y - sh * s1.y);
                s[r1] = make_float2(sh * s0.x + ch * s1.x, sh * s0.y + ch * s1.y);
            }
        }
        for (int i = 0; i < DIM; ++i) stv[i] = s[i];
    }
    __syncthreads();

    // state = U @ state : 16 threads, one row each.
    if (tid < DIM) {
        float2 acc = make_float2(0.0f, 0.0f);
        for (int cc = 0; cc < DIM; ++cc)
            acc = cadd(acc, cmul(cur[(tid << 4) | cc], stv[cc]));
        stv2[tid] = acc;
    }
    __syncthreads();

    // encode_ry(state, -y[0]); qk = |state[0]|
    if (tid == 0) {
        float2 s[DIM];
        for (int i = 0; i < DIM; ++i) s[i] = stv2[i];
        for (int w = 0; w < 4; ++w) {
            const float h = -0.5f * y[w];        // -y[0, w]
            const float ch = cosf(h);
            const float sh = sinf(h);
            const int p = 3 - w;
            for (int r0 = 0; r0 < DIM; ++r0) {
                if ((r0 >> p) & 1) continue;
                const int r1 = r0 | (1 << p);
                const float2 s0 = s[r0];
                const float2 s1 = s[r1];
                s[r0] = make_float2(ch * s0.x - sh * s1.x, ch * s0.y - sh * s1.y);
                s[r1] = make_float2(sh * s0.x + ch * s1.x, sh * s0.y + ch * s1.y);
            }
        }
        const float2 a0 = s[0];
        qk_out[0] = sqrtf(a0.x * a0.x + a0.y * a0.y);
    }
}

// Kernel B: memory-bound elementwise. out[b] = 0.5*exp(-||x_b - y_b||^2) + 0.5*qk
__global__ __launch_bounds__(256) void rbf_out_kernel(
    const float4* __restrict__ x, const float4* __restrict__ y,
    const float* __restrict__ qk_ptr, float* __restrict__ out, int B) {
    const int idx = blockIdx.x * blockDim.x + threadIdx.x;
    if (idx >= B) return;
    const float half_qk = 0.5f * qk_ptr[0];
    const float4 xv = x[idx];
    const float4 yv = y[idx];
    const float dx = xv.x - yv.x;
    const float dy = xv.y - yv.y;
    const float dz = xv.z - yv.z;
    const float dw = xv.w - yv.w;
    const float ss = dx * dx + dy * dy + dz * dz + dw * dw;
    out[idx] = 0.5f * expf(-ss) + half_qk;
}

extern "C" void kernel_launch(void* const* d_in, const int* in_sizes, int n_in,
                              void* d_out, int out_size, void* d_ws, size_t ws_size,
                              hipStream_t stream) {
    const float* x = (const float*)d_in[0];            // (B, 4) f32
    const float* y = (const float*)d_in[1];            // (B, 4) f32
    const float* rand_angles = (const float*)d_in[2];  // (30,)  f32
    const float* rx_param = (const float*)d_in[3];     // (1,)   f32
    const float* ry_param = (const float*)d_in[4];     // (1,)   f32
    float* out = (float*)d_out;                        // (B,)   f32
    float* qk = (float*)d_ws;                          // scalar scratch

    const int B = in_sizes[0] / 4;

    build_qk_kernel<<<1, 256, 0, stream>>>(x, y, rand_angles, rx_param, ry_param, qk);

    const int blocks = (B + 255) / 256;
    rbf_out_kernel<<<blocks, 256, 0, stream>>>(
        (const float4*)x, (const float4*)y, qk, out, B);
}

// Round 3
// 83.241 us; speedup vs baseline: 1.1564x; 1.1564x over previous
//
#include <hip/hip_runtime.h>
#include <math.h>

#define DIM 16
#define N_OPS 30

// Kernel A v2: ONE wave (64 threads), registers only, no LDS, no barriers.
// Lane l<16 owns complex amplitude l of the 16-dim state. Gates = shfl_xor
// pair-mixes. Trig for all angles computed lane-parallel once, then
// broadcast via shfl. Writes qk = |amp0_final| to qk_out[0].
//
// Math (verified round 0, absmax 2e-3 pass):
//  wire w lives on bit p = 3-w.
//  RX(t): new = ch*s + (-i*sh)*partner           (both halves)
//  RY(t): new = ch*s + sign*sh*partner, sign = bit ? +1 : -1
//  RZ(t): bit=0: *(ch - i sh); bit=1: *(ch + i sh)
//  CNOT(c=3,t=0): pc=0, pt=3: s' = (l&1) ? shfl_xor(s,8) : s
//  init state  = prod_w (bit_p(l) ? sin(x_w/2) : cos(x_w/2))     (real)
//  final amp0  = sum_l state[l] * prod_w (bit_p(l) ? sin(y_w/2) : cos(y_w/2))
__global__ __launch_bounds__(64) void build_qk_kernel(
    const float* __restrict__ x, const float* __restrict__ y,
    const float* __restrict__ rand_angles, const float* __restrict__ rx_param,
    const float* __restrict__ ry_param, float* __restrict__ qk_out) {
    const int lane = threadIdx.x;  // 0..63, one wave

    // ---- lane-parallel trig ----
    // lane 0..29  : 0.5*rand_angles[lane]
    // lane 30     : 0.5*rx_param[0]
    // lane 31     : 0.5*ry_param[0]
    // lane 32..35 : 0.5*x[lane-32]   (batch row 0)
    // lane 36..39 : 0.5*y[lane-36]
    float h = 0.0f;
    if (lane < N_OPS)           h = 0.5f * rand_angles[lane];
    else if (lane == 30)        h = 0.5f * rx_param[0];
    else if (lane == 31)        h = 0.5f * ry_param[0];
    else if (lane >= 32 && lane < 36) h = 0.5f * x[lane - 32];
    else if (lane >= 36 && lane < 40) h = 0.5f * y[lane - 36];
    float sh_l, ch_l;
    __sincosf(h, &sh_l, &ch_l);

    // ---- initial state: encode_ry(|0>, x0) = ⊗_w (cos, sin) ----
    float sr = 1.0f, si = 0.0f;
    #pragma unroll
    for (int w = 0; w < 4; ++w) {
        const int p = 3 - w;
        const float cw = __shfl(ch_l, 32 + w);
        const float sw = __shfl(sh_l, 32 + w);
        sr *= ((lane >> p) & 1) ? sw : cw;
    }

    // ---- 30 random-layer gates ----
    #pragma unroll
    for (int i = 0; i < N_OPS; ++i) {
        const int t = i & 3;           // == wire
        const float ch = __shfl(ch_l, i);
        const float sh = __shfl(sh_l, i);
        if (t == 0) {                  // RX on wire 0, p=3
            const float pr = __shfl_xor(sr, 8);
            const float pi = __shfl_xor(si, 8);
            const float nr = ch * sr + sh * pi;
            const float ni = ch * si - sh * pr;
            sr = nr; si = ni;
        } else if (t == 1) {           // RY on wire 1, p=2
            const float pr = __shfl_xor(sr, 4);
            const float pi = __shfl_xor(si, 4);
            const float sg = ((lane >> 2) & 1) ? sh : -sh;
            const float nr = ch * sr + sg * pr;
            const float ni = ch * si + sg * pi;
            sr = nr; si = ni;
        } else if (t == 2) {           // RZ on wire 2, p=1
            const float sg = ((lane >> 1) & 1) ? sh : -sh;
            const float nr = ch * sr - sg * si;
            const float ni = ch * si + sg * sr;
            sr = nr; si = ni;
        } else {                       // CNOT(control=3, target=0): pc=0, pt=3
            const float pr = __shfl_xor(sr, 8);
            const float pi = __shfl_xor(si, 8);
            if (lane & 1) { sr = pr; si = pi; }
        }
    }

    // ---- trainable layer: per wire w: RX(rx) then RY(ry) ----
    const float chx = __shfl(ch_l, 30), shx = __shfl(sh_l, 30);
    const float chy = __shfl(ch_l, 31), shy = __shfl(sh_l, 31);
    #pragma unroll
    for (int w = 0; w < 4; ++w) {
        const int p = 3 - w;
        {   // RX
            const float pr = __shfl_xor(sr, 1 << p);
            const float pi = __shfl_xor(si, 1 << p);
            const float nr = chx * sr + shx * pi;
            const float ni = chx * si - shx * pr;
            sr = nr; si = ni;
        }
        {   // RY
            const float pr = __shfl_xor(sr, 1 << p);
            const float pi = __shfl_xor(si, 1 << p);
            const float sg = ((lane >> p) & 1) ? shy : -shy;
            const float nr = chy * sr + sg * pr;
            const float ni = chy * si + sg * pi;
            sr = nr; si = ni;
        }
    }

    // ---- final: amp0 = sum_l weight_y[l] * s[l]; qk = |amp0| ----
    float wy = 1.0f;
    #pragma unroll
    for (int w = 0; w < 4; ++w) {
        const int p = 3 - w;
        const float cw = __shfl(ch_l, 36 + w);
        const float sw = __shfl(sh_l, 36 + w);
        wy *= ((lane >> p) & 1) ? sw : cw;
    }
    float ar = wy * sr;
    float ai = wy * si;
    #pragma unroll
    for (int m = 8; m >= 1; m >>= 1) {
        ar += __shfl_xor(ar, m);
        ai += __shfl_xor(ai, m);
    }
    if (lane == 0) qk_out[0] = sqrtf(ar * ar + ai * ai);
}

// Kernel B: memory-bound elementwise. out[b] = 0.5*exp(-||x_b - y_b||^2) + 0.5*qk
__global__ __launch_bounds__(256) void rbf_out_kernel(
    const float4* __restrict__ x, const float4* __restrict__ y,
    const float* __restrict__ qk_ptr, float* __restrict__ out, int B) {
    const int idx = blockIdx.x * blockDim.x + threadIdx.x;
    if (idx >= B) return;
    const float half_qk = 0.5f * qk_ptr[0];
    const float4 xv = x[idx];
    const float4 yv = y[idx];
    const float dx = xv.x - yv.x;
    const float dy = xv.y - yv.y;
    const float dz = xv.z - yv.z;
    const float dw = xv.w - yv.w;
    const float ss = dx * dx + dy * dy + dz * dz + dw * dw;
    out[idx] = 0.5f * expf(-ss) + half_qk;
}

extern "C" void kernel_launch(void* const* d_in, const int* in_sizes, int n_in,
                              void* d_out, int out_size, void* d_ws, size_t ws_size,
                              hipStream_t stream) {
    const float* x = (const float*)d_in[0];            // (B, 4) f32
    const float* y = (const float*)d_in[1];            // (B, 4) f32
    const float* rand_angles = (const float*)d_in[2];  // (30,)  f32
    const float* rx_param = (const float*)d_in[3];     // (1,)   f32
    const float* ry_param = (const float*)d_in[4];     // (1,)   f32
    float* out = (float*)d_out;                        // (B,)   f32
    float* qk = (float*)d_ws;                          // scalar scratch

    const int B = in_sizes[0] / 4;

    build_qk_kernel<<<1, 64, 0, stream>>>(x, y, rand_angles, rx_param, ry_param, qk);

    const int blocks = (B + 255) / 256;
    rbf_out_kernel<<<blocks, 256, 0, stream>>>(
        (const float4*)x, (const float4*)y, qk, out, B);
}

// Round 5
// 82.464 us; speedup vs baseline: 1.1673x; 1.0094x over previous
//
#include <hip/hip_runtime.h>
#include <math.h>

#define DIM 16
#define N_OPS 30

// Fused single kernel.
// out[b] = 0.5*exp(-||x_b - y_b||^2) + 0.5*qk, where qk is a batch-independent
// scalar: |<0| E(-y0) * G38 * E(x0) |0>| over a 16-dim state (4 wires).
//
// qk is recomputed redundantly by wave 0 of EVERY block (~400 wave-inst,
// ~0.7 us aggregate chip-wide at 2048 blocks — hidden under the 6 us memory
// stream). This removes the separate 1-wave kernel + its launch + its serial
// time from the critical path, and removes the d_ws dependency entirely.
//
// qk math (verified: passed absmax 2e-3 in rounds 1/3):
//  wire w lives on bit p = 3-w; lane l<16 of wave 0 owns amplitude l.
//  RX: new = ch*s - i*sh*partner        (shfl_xor pair-mix)
//  RY: new = ch*s + (bit? +1:-1)*sh*partner
//  RZ: bit=0: *(ch - i*sh); bit=1: *(ch + i*sh)
//  CNOT(c=3,t=0): s' = (l&1) ? shfl_xor(s,8) : s
//  init state = prod_w (bit_p(l) ? sin(x_w/2) : cos(x_w/2))
//  amp0 = sum_l state[l] * prod_w (bit_p(l) ? sin(y_w/2) : cos(y_w/2))
__global__ __launch_bounds__(256) void fused_hybrid_kernel(
    const float4* __restrict__ x4, const float4* __restrict__ y4,
    const float* __restrict__ x, const float* __restrict__ y,
    const float* __restrict__ rand_angles, const float* __restrict__ rx_param,
    const float* __restrict__ ry_param, float* __restrict__ out, int B) {
    __shared__ float s_qk;

    const int tid = threadIdx.x;
    const int i0 = blockIdx.x * 512 + tid;        // element index, chunk 0
    const int i1 = i0 + 256;                      // element index, chunk 1

    // ---- issue the batch loads FIRST (all waves, memory in flight) ----
    float r0 = 0.0f, r1 = 0.0f;
    if (i0 < B) {
        const float4 xv = x4[i0];
        const float4 yv = y4[i0];
        const float dx = xv.x - yv.x, dy = xv.y - yv.y;
        const float dz = xv.z - yv.z, dw = xv.w - yv.w;
        r0 = 0.5f * __expf(-(dx * dx + dy * dy + dz * dz + dw * dw));
    }
    if (i1 < B) {
        const float4 xv = x4[i1];
        const float4 yv = y4[i1];
        const float dx = xv.x - yv.x, dy = xv.y - yv.y;
        const float dz = xv.z - yv.z, dw = xv.w - yv.w;
        r1 = 0.5f * __expf(-(dx * dx + dy * dy + dz * dz + dw * dw));
    }

    // ---- wave 0: redundant qk sim, registers + shfl only ----
    if (tid < 64) {
        const int lane = tid;
        // lane-parallel trig: lanes 0..29 rand, 30 rx, 31 ry, 32..35 x0, 36..39 y0
        float h = 0.0f;
        if (lane < N_OPS)                 h = 0.5f * rand_angles[lane];
        else if (lane == 30)              h = 0.5f * rx_param[0];
        else if (lane == 31)              h = 0.5f * ry_param[0];
        else if (lane >= 32 && lane < 36) h = 0.5f * x[lane - 32];
        else if (lane >= 36 && lane < 40) h = 0.5f * y[lane - 36];
        float sh_l, ch_l;
        __sincosf(h, &sh_l, &ch_l);

        // initial state = per-lane product of (cos, sin) of x0
        float sr = 1.0f, si = 0.0f;
        #pragma unroll
        for (int w = 0; w < 4; ++w) {
            const int p = 3 - w;
            const float cw = __shfl(ch_l, 32 + w);
            const float sw = __shfl(sh_l, 32 + w);
            sr *= ((lane >> p) & 1) ? sw : cw;
        }

        // 30 random-layer gates
        #pragma unroll
        for (int i = 0; i < N_OPS; ++i) {
            const int t = i & 3;
            const float ch = __shfl(ch_l, i);
            const float sh = __shfl(sh_l, i);
            if (t == 0) {                  // RX wire0, p=3
                const float pr = __shfl_xor(sr, 8);
                const float pi = __shfl_xor(si, 8);
                const float nr = ch * sr + sh * pi;
                const float ni = ch * si - sh * pr;
                sr = nr; si = ni;
            } else if (t == 1) {           // RY wire1, p=2
                const float pr = __shfl_xor(sr, 4);
                const float pi = __shfl_xor(si, 4);
                const float sg = ((lane >> 2) & 1) ? sh : -sh;
                const float nr = ch * sr + sg * pr;
                const float ni = ch * si + sg * pi;
                sr = nr; si = ni;
            } else if (t == 2) {           // RZ wire2, p=1
                const float sg = ((lane >> 1) & 1) ? sh : -sh;
                const float nr = ch * sr - sg * si;
                const float ni = ch * si + sg * sr;
                sr = nr; si = ni;
            } else {                       // CNOT(control=3, target=0)
                const float pr = __shfl_xor(sr, 8);
                const float pi = __shfl_xor(si, 8);
                if (lane & 1) { sr = pr; si = pi; }
            }
        }

        // trainable layer: per wire: RX(rx) then RY(ry)
        const float chx = __shfl(ch_l, 30), shx = __shfl(sh_l, 30);
        const float chy = __shfl(ch_l, 31), shy = __shfl(sh_l, 31);
        #pragma unroll
        for (int w = 0; w < 4; ++w) {
            const int p = 3 - w;
            {   // RX
                const float pr = __shfl_xor(sr, 1 << p);
                const float pi = __shfl_xor(si, 1 << p);
                const float nr = chx * sr + shx * pi;
                const float ni = chx * si - shx * pr;
                sr = nr; si = ni;
            }
            {   // RY
                const float pr = __shfl_xor(sr, 1 << p);
                const float pi = __shfl_xor(si, 1 << p);
                const float sg = ((lane >> p) & 1) ? shy : -shy;
                const float nr = chy * sr + sg * pr;
                const float ni = chy * si + sg * pi;
                sr = nr; si = ni;
            }
        }

        // amp0 = sum_l weight_y[l] * s[l]; qk = |amp0|
        float wy = 1.0f;
        #pragma unroll
        for (int w = 0; w < 4; ++w) {
            const int p = 3 - w;
            const float cw = __shfl(ch_l, 36 + w);
            const float sw = __shfl(sh_l, 36 + w);
            wy *= ((lane >> p) & 1) ? sw : cw;
        }
        float ar = wy * sr;
        float ai = wy * si;
        #pragma unroll
        for (int m = 8; m >= 1; m >>= 1) {
            ar += __shfl_xor(ar, m);
            ai += __shfl_xor(ai, m);
        }
        if (lane == 0) s_qk = 0.5f * sqrtf(ar * ar + ai * ai);
    }
    __syncthreads();

    const float hq = s_qk;
    if (i0 < B) out[i0] = r0 + hq;
    if (i1 < B) out[i1] = r1 + hq;
}

extern "C" void kernel_launch(void* const* d_in, const int* in_sizes, int n_in,
                              void* d_out, int out_size, void* d_ws, size_t ws_size,
                              hipStream_t stream) {
    const float* x = (const float*)d_in[0];            // (B, 4) f32
    const float* y = (const float*)d_in[1];            // (B, 4) f32
    const float* rand_angles = (const float*)d_in[2];  // (30,)  f32
    const float* rx_param = (const float*)d_in[3];     // (1,)   f32
    const float* ry_param = (const float*)d_in[4];     // (1,)   f32
    float* out = (float*)d_out;                        // (B,)   f32

    const int B = in_sizes[0] / 4;                     // rows (float4 count)
    const int blocks = (B + 511) / 512;                // 2 rows per thread

    fused_hybrid_kernel<<<blocks, 256, 0, stream>>>(
        (const float4*)x, (const float4*)y, x, y,
        rand_angles, rx_param, ry_param, out, B);
}